// Round 1
// baseline (267.662 us; speedup 1.0000x reference)
//
#include <hip/hip_runtime.h>
#include <hip/hip_bf16.h>

// Binarized-weight conv2d: x[32][256][56][56] (f32), W[256][256][3][3] (f32, sign-binarized)
// -> out[32][256][56][56] (f32), stride 1, pad 1.
// Strategy: bf16 MFMA implicit GEMM. M=100352 pixels, N=256 c_out, K=2304.

#define N_IMG   32
#define C_IN    256
#define C_OUT   256
#define HW      56
#define HP      58          // padded spatial
#define PIX     (HW*HW)     // 3136 pixels per image
#define M_TOT   (N_IMG*PIX) // 100352
#define K_TOT   (C_IN*9)    // 2304

#define WB_BYTES   (C_OUT * K_TOT * 2)            // 1,179,648
#define XPAD_ELEMS (N_IMG * HP * HP * C_IN)       // 27,557,888
#define XPAD_BYTES (XPAD_ELEMS * 2)               // 55,115,776
#define WS_NEEDED  (WB_BYTES + XPAD_BYTES)

typedef short  bf16x8 __attribute__((ext_vector_type(8)));
typedef float  f32x4  __attribute__((ext_vector_type(4)));

// ---------------- W binarize + reorder: OIHW f32 -> [co][khkw*256+ci] bf16 (+-1.0)
__global__ void __launch_bounds__(256) binW_kernel(const float* __restrict__ W,
                                                   unsigned short* __restrict__ wb) {
    int i = blockIdx.x * 256 + threadIdx.x;          // i over C_OUT*K_TOT = 589824
    int co = i / K_TOT;
    int k  = i - co * K_TOT;
    int khkw = k >> 8;                               // 0..8
    int ci   = k & 255;
    float v = W[co * K_TOT + ci * 9 + khkw];
    wb[i] = (v >= 0.f) ? 0x3F80u : 0xBF80u;          // +1.0 / -1.0 bf16
}

// ---------------- x: f32 NCHW -> bf16 NHWC padded [n][h+1][w+1][ci]
__global__ void __launch_bounds__(256) transpose_pad_kernel(const float* __restrict__ x,
                                                            unsigned short* __restrict__ xp) {
    __shared__ __align__(16) unsigned short s[HW * 258];  // s[w][ci], stride 258 (odd dword -> conflict-free)
    const int t = threadIdx.x;
    const int h = blockIdx.x;        // 0..55
    const int n = blockIdx.y;        // 0..31
    const float* xrow = x + ((n * C_IN) * HW + h) * HW;   // + ci*3136 + w

    #pragma unroll 4
    for (int i = 0; i < 64; ++i) {                   // 256ci x 64(w padded to 64)
        int idx = i * 256 + t;
        int ci = idx >> 6, w = idx & 63;
        if (w < HW) {
            float v = xrow[ci * PIX + w];
            __hip_bfloat16 b = __float2bfloat16(v);
            s[w * 258 + ci] = reinterpret_cast<unsigned short&>(b);
        }
    }
    __syncthreads();
    // store: 56*256 bf16 = 7168 dwords, coalesced along ci
    #pragma unroll 4
    for (int i = 0; i < 28; ++i) {
        int idx = i * 256 + t;                       // dword index
        int w = idx >> 7, cp = idx & 127;            // cp = ci pair
        unsigned int d = *(const unsigned int*)&s[w * 258 + cp * 2];
        unsigned int off = ((n * HP + h + 1) * HP + (w + 1)) * C_IN + cp * 2;
        *(unsigned int*)&xp[off] = d;
    }
}

// ---------------- main implicit GEMM (m97 structure: 128x128 tile, BK=64, 4 waves)
__global__ void __launch_bounds__(256) conv_gemm_kernel(const __hip_bfloat16* __restrict__ xpad,
                                                        const __hip_bfloat16* __restrict__ wb,
                                                        float* __restrict__ out) {
    __shared__ __hip_bfloat16 Ws[128 * 64];   // [co_local][k_local] 16KB
    __shared__ __hip_bfloat16 Xs[128 * 64];   // [px_local][k_local] 16KB
    __shared__ int rowbase[128];

    const int t    = threadIdx.x;
    const int lane = t & 63;
    const int wid  = t >> 6;
    const int co0  = blockIdx.x * 128;    // 2 tiles: consecutive blocks share the A(x) panel
    const int m0   = blockIdx.y * 128;    // 784 tiles

    // per-row im2col base: ((n*58 + h)*58 + w)*256  (kh,kw shift added per K-step)
    if (t < 128) {
        int m = m0 + t;
        int n = m / PIX;
        int p = m - n * PIX;
        int h = p / HW;
        int w = p - h * HW;
        rowbase[t] = ((n * HP + h) * HP + w) * C_IN;
    }
    __syncthreads();

    const int rrow  = t >> 3;   // 0..31 : row within staging issue
    const int chunk = t & 7;    // 0..7  : 16B chunk within 128B row
    int rb[4];
    int wsrc[4];
    #pragma unroll
    for (int i = 0; i < 4; ++i) {
        rb[i]   = rowbase[i * 32 + rrow];
        wsrc[i] = (co0 + i * 32 + rrow) * K_TOT + chunk * 8;
    }

    f32x4 acc[4][4];
    #pragma unroll
    for (int i = 0; i < 4; ++i)
        #pragma unroll
        for (int j = 0; j < 4; ++j)
            acc[i][j] = (f32x4){0.f, 0.f, 0.f, 0.f};

    const int wco = wid >> 1;   // 0/1 : which 64-co half
    const int wpx = wid & 1;    // 0/1 : which 64-px half
    const int l15 = lane & 15;
    const int l4  = lane >> 4;

    for (int ks = 0; ks < 36; ++ks) {
        const int khkw = ks >> 2;
        const int kh   = khkw / 3;
        const int kw   = khkw - kh * 3;
        const int xoff = (kh * HP + kw) * C_IN + ((ks & 3) << 6);  // scalar per step
        const int k0   = ks << 6;

        __syncthreads();   // previous compute done -> safe to overwrite LDS
        #pragma unroll
        for (int i = 0; i < 4; ++i) {
            __builtin_amdgcn_global_load_lds(
                (const __attribute__((address_space(1))) void*)(wb + wsrc[i] + k0),
                (__attribute__((address_space(3))) void*)((char*)Ws + i * 4096 + t * 16),
                16, 0, 0);
            __builtin_amdgcn_global_load_lds(
                (const __attribute__((address_space(1))) void*)(xpad + rb[i] + xoff + chunk * 8),
                (__attribute__((address_space(3))) void*)((char*)Xs + i * 4096 + t * 16),
                16, 0, 0);
        }
        __syncthreads();   // drains vmcnt(0): tiles resident

        #pragma unroll
        for (int kk = 0; kk < 2; ++kk) {
            bf16x8 af[4], bx[4];
            #pragma unroll
            for (int i = 0; i < 4; ++i)
                af[i] = *(const bf16x8*)&Ws[(wco * 64 + i * 16 + l15) * 64 + kk * 32 + l4 * 8];
            #pragma unroll
            for (int j = 0; j < 4; ++j)
                bx[j] = *(const bf16x8*)&Xs[(wpx * 64 + j * 16 + l15) * 64 + kk * 32 + l4 * 8];
            #pragma unroll
            for (int i = 0; i < 4; ++i)
                #pragma unroll
                for (int j = 0; j < 4; ++j)
                    acc[i][j] = __builtin_amdgcn_mfma_f32_16x16x32_bf16(af[i], bx[j], acc[i][j], 0, 0, 0);
        }
    }

    // epilogue: C[co][px] -> out[n][co][h][w]; col=lane&15 (px, contiguous), row=(lane>>4)*4+r (co)
    #pragma unroll
    for (int j = 0; j < 4; ++j) {
        int mg = m0 + wpx * 64 + j * 16;     // 16-aligned, within one image (3136 % 16 == 0)
        int n  = mg / PIX;
        int p  = mg - n * PIX;
        float* obase = out + (n * C_OUT) * PIX + p + l15;
        #pragma unroll
        for (int i = 0; i < 4; ++i) {
            int co = co0 + wco * 64 + i * 16 + l4 * 4;
            #pragma unroll
            for (int r = 0; r < 4; ++r)
                obase[(co + r) * PIX] = acc[i][j][r];
        }
    }
}

// ---------------- fallback (ws too small): naive direct conv, correct but slow
__global__ void __launch_bounds__(256) conv_naive_kernel(const float* __restrict__ x,
                                                         const float* __restrict__ W,
                                                         float* __restrict__ out) {
    int idx = blockIdx.x * 256 + threadIdx.x;
    if (idx >= M_TOT * 8) return;            // guard (grid sized exactly anyway)
    int w = idx % HW;
    int tmp = idx / HW;
    int h = tmp % HW;
    tmp /= HW;
    int co = tmp & 255;
    int n  = tmp >> 8;
    const float* xn = x + n * (C_IN * PIX);
    const float* wc = W + co * K_TOT;
    float acc = 0.f;
    for (int ci = 0; ci < C_IN; ++ci) {
        const float* xc = xn + ci * PIX;
        const float* wk = wc + ci * 9;
        #pragma unroll
        for (int kh = 0; kh < 3; ++kh) {
            int hh = h + kh - 1;
            if (hh < 0 || hh >= HW) continue;
            #pragma unroll
            for (int kw = 0; kw < 3; ++kw) {
                int ww = w + kw - 1;
                if (ww < 0 || ww >= HW) continue;
                float xv = xc[hh * HW + ww];
                acc += (wk[kh * 3 + kw] >= 0.f) ? xv : -xv;
            }
        }
    }
    out[idx] = acc;
}

extern "C" void kernel_launch(void* const* d_in, const int* in_sizes, int n_in,
                              void* d_out, int out_size, void* d_ws, size_t ws_size,
                              hipStream_t stream) {
    const float* x = (const float*)d_in[0];
    const float* W = (const float*)d_in[1];
    float* out = (float*)d_out;

    if (ws_size < (size_t)WS_NEEDED) {
        // not enough scratch: slow correct path
        int total = N_IMG * C_OUT * PIX;
        conv_naive_kernel<<<(total + 255) / 256, 256, 0, stream>>>(x, W, out);
        return;
    }

    unsigned short* wb   = (unsigned short*)d_ws;
    __hip_bfloat16* xpad = (__hip_bfloat16*)((char*)d_ws + WB_BYTES);

    hipMemsetAsync(xpad, 0, XPAD_BYTES, stream);   // zero halo (interior overwritten)
    binW_kernel<<<(C_OUT * K_TOT) / 256, 256, 0, stream>>>(W, wb);
    transpose_pad_kernel<<<dim3(HW, N_IMG), 256, 0, stream>>>(x, (unsigned short*)xpad);
    conv_gemm_kernel<<<dim3(2, M_TOT / 128), 256, 0, stream>>>(xpad, (const __hip_bfloat16*)wb, out);
}

// Round 2
// 176.147 us; speedup vs baseline: 1.5195x; 1.5195x over previous
//
#include <hip/hip_runtime.h>
#include <hip/hip_bf16.h>

// Binarized-weight conv2d: x[32][256][56][56] (f32), W[256][256][3][3] (sign)
// -> out[32][256][56][56] (f32), stride 1, pad 1.
// bf16 MFMA implicit GEMM, 8-phase counted-vmcnt schedule (T1+T2+T3+T4+T5).
// M=100352 px, N=256 c_out, K=2304. Block tile: 224px x 256co, BK=64, 8 waves.

#define N_IMG   32
#define C_IN    256
#define C_OUT   256
#define HW      56
#define HP      58
#define PIX     (HW*HW)      // 3136
#define M_TOT   (N_IMG*PIX)  // 100352
#define K_TOT   (C_IN*9)     // 2304

#define WB_BYTES   (C_OUT * K_TOT * 2)
#define XPAD_ELEMS (N_IMG * HP * HP * C_IN)
#define XPAD_BYTES (XPAD_ELEMS * 2)
#define WS_NEEDED  (WB_BYTES + XPAD_BYTES)

#define BM      224
#define NBLK    (M_TOT / BM)   // 448 = 8*56
#define NT      36             // K tiles of 64
#define NITER   18             // 2 tiles / iter

typedef short  bf16x8 __attribute__((ext_vector_type(8)));
typedef float  f32x4  __attribute__((ext_vector_type(4)));

// ---------------- W binarize + reorder: OIHW f32 -> [co][khkw*256+ci] bf16 (+-1)
__global__ void __launch_bounds__(256) binW_kernel(const float* __restrict__ W,
                                                   unsigned short* __restrict__ wb) {
    int i = blockIdx.x * 256 + threadIdx.x;
    int co = i / K_TOT;
    int k  = i - co * K_TOT;
    int khkw = k >> 8;
    int ci   = k & 255;
    float v = W[co * K_TOT + ci * 9 + khkw];
    wb[i] = (v >= 0.f) ? 0x3F80u : 0xBF80u;
}

// ---------------- x: f32 NCHW -> bf16 NHWC padded [n][h+1][w+1][ci]
__global__ void __launch_bounds__(256) transpose_pad_kernel(const float* __restrict__ x,
                                                            unsigned short* __restrict__ xp) {
    __shared__ __align__(16) unsigned short s[HW * 258];
    const int t = threadIdx.x;
    const int h = blockIdx.x;
    const int n = blockIdx.y;
    const float* xrow = x + ((n * C_IN) * HW + h) * HW;

    #pragma unroll 4
    for (int i = 0; i < 64; ++i) {
        int idx = i * 256 + t;
        int ci = idx >> 6, w = idx & 63;
        if (w < HW) {
            float v = xrow[ci * PIX + w];
            __hip_bfloat16 b = __float2bfloat16(v);
            s[w * 258 + ci] = reinterpret_cast<unsigned short&>(b);
        }
    }
    __syncthreads();
    #pragma unroll 4
    for (int i = 0; i < 28; ++i) {
        int idx = i * 256 + t;
        int w = idx >> 7, cp = idx & 127;
        unsigned int d = *(const unsigned int*)&s[w * 258 + cp * 2];
        unsigned int off = ((n * HP + h + 1) * HP + (w + 1)) * C_IN + cp * 2;
        *(unsigned int*)&xp[off] = d;
    }
}

// ---------------- 8-phase GEMM
// LDS layout (bytes): X halves [buf][ksub] 16KB each at (buf*2+s)*16384 (rows 0..255 x 32k)
//                     W halves at 65536 + (buf*2+s)*16384 (co 0..255 x 32k)
// swizzle: 16B chunk c within 64B row stored at physical chunk c ^ ((row>>1)&3).
#define XB(b,s)  (((b)*2+(s))*16384)
#define WB_(b,s) (65536 + ((b)*2+(s))*16384)

__device__ __forceinline__ int xkoff(int kabs) {     // im2col k offset into xpad
    int khkw = kabs >> 8;
    int kin  = kabs & 255;
    int kh = khkw / 3, kw = khkw % 3;
    return (kh * HP + kw) * C_IN + kin;
}

__global__ void __launch_bounds__(512, 2)
conv_gemm8_kernel(const __hip_bfloat16* __restrict__ xpad,
                  const __hip_bfloat16* __restrict__ wb,
                  float* __restrict__ out) {
    __shared__ __align__(16) unsigned short LDSBUF[65536];   // 128 KiB

    const int t    = threadIdx.x;
    const int lane = t & 63;
    const int wid  = t >> 6;
    const int wpx  = wid >> 2;       // 0..1 : 112-px half
    const int wco  = wid & 3;        // 0..3 : 64-co quarter
    const int l15  = lane & 15;
    const int l4   = lane >> 4;

    int bid = (int)blockIdx.x;
    bid = (bid & 7) * (NBLK / 8) + (bid >> 3);      // T1 XCD swizzle (448 = 8*56)
    const int m0 = bid * BM;

    // read-side LDS byte offsets within a 16KB half-array
    int xrd[7], wrd[4];
    #pragma unroll
    for (int i = 0; i < 7; ++i) {
        int r = wpx * 112 + i * 16 + l15;
        xrd[i] = r * 64 + ((l4 ^ ((r >> 1) & 3)) << 4);
    }
    #pragma unroll
    for (int j = 0; j < 4; ++j) {
        int r = wco * 64 + j * 16 + l15;
        wrd[j] = r * 64 + ((l4 ^ ((r >> 1) & 3)) << 4);
    }

    // stage-side: thread t fills physical 16B slot (row=t>>2 (+128*issue), chunk=t&3);
    // source uses logical chunk lc = (t&3) ^ ((t>>3)&3)  (inverse swizzle on global addr)
    const int lc8 = (((t & 3) ^ ((t >> 3) & 3)) << 3);
    int rb[2], wgb[2];
    #pragma unroll
    for (int j = 0; j < 2; ++j) {
        int row = j * 128 + (t >> 2);
        int m = m0 + row; if (m > M_TOT - 1) m = M_TOT - 1;   // rows 224..255: pad (never read)
        int n = m / PIX;
        int p = m - n * PIX;
        int h = p / HW;
        int w = p - h * HW;
        rb[j]  = ((n * HP + h) * HP + w) * C_IN + lc8;
        wgb[j] = row * K_TOT + lc8;
    }
    const int ldst = t * 16;

#define GLD(gp, off) __builtin_amdgcn_global_load_lds( \
        (const __attribute__((address_space(1))) void*)(gp), \
        (__attribute__((address_space(3))) void*)((char*)LDSBUF + (off)), 16, 0, 0)

#define STAGE_X(b, s, kabs) { int ko_ = xkoff(kabs); \
        GLD(xpad + rb[0] + ko_, XB(b,s) + ldst); \
        GLD(xpad + rb[1] + ko_, XB(b,s) + 8192 + ldst); }

#define STAGE_W(b, s, kabs) { \
        GLD(wb + wgb[0] + (kabs), WB_(b,s) + ldst); \
        GLD(wb + wgb[1] + (kabs), WB_(b,s) + 8192 + ldst); }

#define LDX(dst, i, b, s) dst = *(const bf16x8*)((const char*)LDSBUF + XB(b,s) + xrd[i])
#define LDW(dst, j, b, s) dst = *(const bf16x8*)((const char*)LDSBUF + WB_(b,s) + wrd[j])

    f32x4 acc[7][4];
    #pragma unroll
    for (int i = 0; i < 7; ++i)
        #pragma unroll
        for (int j = 0; j < 4; ++j)
            acc[i][j] = (f32x4){0.f, 0.f, 0.f, 0.f};

    bf16x8 xfA[4], wfA[4], xfB[3];

    // PH0: read full subtile (4 X + 4 W), 16 MFMA.  PH1: read 3 X, 12 MFMA (reuse wfA).
#define PH0(b, s, STG, EV) { \
        LDX(xfA[0],0,b,s); LDX(xfA[1],1,b,s); LDX(xfA[2],2,b,s); LDX(xfA[3],3,b,s); \
        LDW(wfA[0],0,b,s); LDW(wfA[1],1,b,s); LDW(wfA[2],2,b,s); LDW(wfA[3],3,b,s); \
        STG; \
        __builtin_amdgcn_sched_barrier(0); \
        __builtin_amdgcn_s_barrier(); \
        __builtin_amdgcn_s_setprio(1); \
        _Pragma("unroll") \
        for (int i_ = 0; i_ < 4; ++i_) \
            _Pragma("unroll") \
            for (int j_ = 0; j_ < 4; ++j_) \
                acc[i_][j_] = __builtin_amdgcn_mfma_f32_16x16x32_bf16(wfA[j_], xfA[i_], acc[i_][j_], 0, 0, 0); \
        __builtin_amdgcn_s_setprio(0); \
        if (EV) asm volatile("s_waitcnt vmcnt(8)" ::: "memory"); \
        __builtin_amdgcn_sched_barrier(0); \
        __builtin_amdgcn_s_barrier(); \
    }

#define PH1(b, s, STG, EV) { \
        LDX(xfB[0],4,b,s); LDX(xfB[1],5,b,s); LDX(xfB[2],6,b,s); \
        STG; \
        __builtin_amdgcn_sched_barrier(0); \
        __builtin_amdgcn_s_barrier(); \
        __builtin_amdgcn_s_setprio(1); \
        _Pragma("unroll") \
        for (int i_ = 0; i_ < 3; ++i_) \
            _Pragma("unroll") \
            for (int j_ = 0; j_ < 4; ++j_) \
                acc[4 + i_][j_] = __builtin_amdgcn_mfma_f32_16x16x32_bf16(wfA[j_], xfB[i_], acc[4 + i_][j_], 0, 0, 0); \
        __builtin_amdgcn_s_setprio(0); \
        if (EV) asm volatile("s_waitcnt vmcnt(8)" ::: "memory"); \
        __builtin_amdgcn_sched_barrier(0); \
        __builtin_amdgcn_s_barrier(); \
    }

    // prologue: tile0 all 4 halves -> buf0; tile1 k0 halves -> buf1 (12 issues)
    STAGE_X(0, 0, 0);  STAGE_W(0, 0, 0);
    STAGE_X(0, 1, 32); STAGE_W(0, 1, 32);
    STAGE_X(1, 0, 64); STAGE_W(1, 0, 64);
    asm volatile("s_waitcnt vmcnt(8)" ::: "memory");   // tile0 k0 halves landed
    __builtin_amdgcn_sched_barrier(0);
    __builtin_amdgcn_s_barrier();

    #pragma unroll 1
    for (int it = 0; it < NITER; ++it) {
        const int to = 2 * it + 1;
        int t2 = 2 * it + 2; if (t2 > NT - 1) t2 = NT - 1;   // clamped over-stage (garbage, never read)
        int t3 = 2 * it + 3; if (t3 > NT - 1) t3 = NT - 1;

        // phases 1-4: compute tile 2i (buf0)
        PH0(0, 0, STAGE_X(1, 1, to * 64 + 32), 0);   // ph1
        PH1(0, 0, STAGE_W(1, 1, to * 64 + 32), 1);   // ph2  vmcnt(8)
        PH0(0, 1, STAGE_X(0, 0, t2 * 64), 0);        // ph3
        PH1(0, 1, STAGE_W(0, 0, t2 * 64), 1);        // ph4  vmcnt(8)
        // phases 5-8: compute tile 2i+1 (buf1)
        PH0(1, 0, STAGE_X(0, 1, t2 * 64 + 32), 0);   // ph5
        PH1(1, 0, STAGE_W(0, 1, t2 * 64 + 32), 1);   // ph6  vmcnt(8)
        PH0(1, 1, STAGE_X(1, 0, t3 * 64), 0);        // ph7
        PH1(1, 1, STAGE_W(1, 0, t3 * 64), 1);        // ph8  vmcnt(8)
    }

    // epilogue: C row=co (l4*4+r), col=px (l15)
    const int nimg = m0 / PIX;                // exact: 3136 = 14*224
    const int p0   = m0 - nimg * PIX;
    float* ob = out + nimg * (C_OUT * PIX);
    #pragma unroll
    for (int i = 0; i < 7; ++i) {
        int p = p0 + wpx * 112 + i * 16 + l15;
        #pragma unroll
        for (int j = 0; j < 4; ++j) {
            int co = wco * 64 + j * 16 + l4 * 4;
            #pragma unroll
            for (int r = 0; r < 4; ++r)
                ob[(co + r) * PIX + p] = acc[i][j][r];
        }
    }
#undef PH0
#undef PH1
#undef GLD
#undef STAGE_X
#undef STAGE_W
#undef LDX
#undef LDW
}

// ---------------- fallback: naive direct conv
__global__ void __launch_bounds__(256) conv_naive_kernel(const float* __restrict__ x,
                                                         const float* __restrict__ W,
                                                         float* __restrict__ out) {
    int idx = blockIdx.x * 256 + threadIdx.x;
    int w = idx % HW;
    int tmp = idx / HW;
    int h = tmp % HW;
    tmp /= HW;
    int co = tmp & 255;
    int n  = tmp >> 8;
    const float* xn = x + n * (C_IN * PIX);
    const float* wc = W + co * K_TOT;
    float acc = 0.f;
    for (int ci = 0; ci < C_IN; ++ci) {
        const float* xc = xn + ci * PIX;
        const float* wk = wc + ci * 9;
        #pragma unroll
        for (int kh = 0; kh < 3; ++kh) {
            int hh = h + kh - 1;
            if (hh < 0 || hh >= HW) continue;
            #pragma unroll
            for (int kw = 0; kw < 3; ++kw) {
                int ww = w + kw - 1;
                if (ww < 0 || ww >= HW) continue;
                float xv = xc[hh * HW + ww];
                acc += (wk[kh * 3 + kw] >= 0.f) ? xv : -xv;
            }
        }
    }
    out[idx] = acc;
}

extern "C" void kernel_launch(void* const* d_in, const int* in_sizes, int n_in,
                              void* d_out, int out_size, void* d_ws, size_t ws_size,
                              hipStream_t stream) {
    const float* x = (const float*)d_in[0];
    const float* W = (const float*)d_in[1];
    float* out = (float*)d_out;

    if (ws_size < (size_t)WS_NEEDED) {
        int total = N_IMG * C_OUT * PIX;
        conv_naive_kernel<<<(total + 255) / 256, 256, 0, stream>>>(x, W, out);
        return;
    }

    unsigned short* wb   = (unsigned short*)d_ws;
    __hip_bfloat16* xpad = (__hip_bfloat16*)((char*)d_ws + WB_BYTES);

    hipMemsetAsync(xpad, 0, XPAD_BYTES, stream);
    binW_kernel<<<(C_OUT * K_TOT) / 256, 256, 0, stream>>>(W, wb);
    transpose_pad_kernel<<<dim3(HW, N_IMG), 256, 0, stream>>>(x, (unsigned short*)wb == nullptr ? nullptr : (unsigned short*)xpad);
    conv_gemm8_kernel<<<dim3(NBLK), 512, 0, stream>>>(xpad, (const __hip_bfloat16*)wb, out);
}